// Round 21
// baseline (170.114 us; speedup 1.0000x reference)
//
#include <hip/hip_runtime.h>
#include <math.h>

#define N_NODES 100000
#define N_EDGES 800000
#define DIM_IN 128
#define DIM_OUT 256
#define NPB 64    // nodes per fused block: 2 MFMA sub-tiles of 32, 8 agg-nodes/wave
#define CAP 64    // padded CSR capacity; deg ~ Poisson(8), P(>=64) ~ 1e-36

typedef __bf16 bf16x8 __attribute__((ext_vector_type(8)));
typedef float  f32x4  __attribute__((ext_vector_type(4)));

// ---------------- prep: cvtX + cvtW + zero cnt (no atomics) ----------------
__global__ __launch_bounds__(256) void k_prep(const float* __restrict__ x,
                                              const float* __restrict__ W,
                                              unsigned short* __restrict__ xb,
                                              unsigned short* __restrict__ Wb,
                                              int* __restrict__ cnt) {
    int i = blockIdx.x * 256 + threadIdx.x;
    const float4 v = reinterpret_cast<const float4*>(x)[i];
    unsigned short s0 = __builtin_bit_cast(unsigned short, (__bf16)v.x);
    unsigned short s1 = __builtin_bit_cast(unsigned short, (__bf16)v.y);
    unsigned short s2 = __builtin_bit_cast(unsigned short, (__bf16)v.z);
    unsigned short s3 = __builtin_bit_cast(unsigned short, (__bf16)v.w);
    uint2 o;
    o.x = (unsigned)s0 | ((unsigned)s1 << 16);
    o.y = (unsigned)s2 | ((unsigned)s3 << 16);
    reinterpret_cast<uint2*>(xb)[i] = o;
    if (i < DIM_IN * DIM_OUT) Wb[i] = __builtin_bit_cast(unsigned short, (__bf16)W[i]);
    if (i < N_NODES) cnt[i] = 0;
}

// ---------------- padded-bucket CSR fill -----------------------------------
__global__ __launch_bounds__(256) void k_fillpad(const int* __restrict__ src,
                                                 const int* __restrict__ dst,
                                                 int* __restrict__ cnt,
                                                 int* __restrict__ list) {
    int e = blockIdx.x * 256 + threadIdx.x;   // grid exact: 800000/256
    int d = dst[e];
    int pos = atomicAdd(&cnt[d], 1);
    if (pos < CAP) list[(size_t)d * CAP + pos] = src[e];
}

// ---------------- helpers ---------------------------------------------------
__device__ __forceinline__ float bflo(unsigned u) {
    return __builtin_bit_cast(float, u << 16);
}
__device__ __forceinline__ float bfhi(unsigned u) {
    return __builtin_bit_cast(float, u & 0xffff0000u);
}
__device__ __forceinline__ float gelu_f(float h) {
    float u = h * h;
    float inner = h * (0.7978845608f + 0.0356774081f * u);
    float a = __builtin_amdgcn_exp2f(-2.8853900818f * __builtin_fabsf(inner));
    float t = (1.f - a) * __builtin_amdgcn_rcpf(1.f + a);
    t = __builtin_copysignf(t, inner);
    return 0.5f * h * (1.f + t);
}

// ---------------- FUSED aggregate + MFMA GEMM + bias + GELU ----------------
// R20 failure diagnosed: full #pragma unroll on the 8-node agg loop caused a
// 44-VGPR pressure-collapse schedule (W re-loaded inside the MFMA loop, no
// spill traffic but serialized). Fix: unroll 1 -> per-iteration pressure ==
// standalone agg; phase 2 allocates like R18's proven gemm (same bounds).
__global__ __launch_bounds__(512, 4) void k_aggemm(
    const unsigned short* __restrict__ xb,
    const int* __restrict__ list,
    const int* __restrict__ cnt,
    const float* __restrict__ deg_inv,
    const unsigned short* __restrict__ Wb,
    const float* __restrict__ bias,
    float* __restrict__ out)
{
    __shared__ unsigned char mtile[NPB * 256];   // 16 KB swizzled bf16 m-tile

    const int tid  = threadIdx.x;
    const int wave = tid >> 6;
    const int lane = tid & 63;
    const int lr = lane & 15;
    const int kg = lane >> 4;
    const int o0 = wave * 32;
    const int nb0 = blockIdx.x * NPB;

    // ===== Phase 1: aggregate 8 nodes per wave into swizzled LDS ===========
    const int gw   = lane >> 2;        // 16B granule holding this lane's 4B
    const int bofs = (lane & 3) * 4;   // byte offset within granule
#pragma unroll 1
    for (int i = 0; i < 8; ++i) {
        const int row  = wave * 8 + i;
        const int node = nb0 + row;
        float r0 = 0.f, r1 = 0.f;
        if (node < N_NODES) {
            int c = __builtin_amdgcn_readfirstlane(cnt[node]);
            c = c < CAP ? c : CAP;
            const int beg = node * CAP;
            const int end = beg + c;
            float a0 = 0.f, a1 = 0.f, b0 = 0.f, b1 = 0.f;
            float c0 = 0.f, c1 = 0.f, d0 = 0.f, d1 = 0.f;
            int e = beg;
            for (; e + 7 < end; e += 8) {
                int s0 = list[e],     s1 = list[e + 1], s2 = list[e + 2], s3 = list[e + 3];
                int s4 = list[e + 4], s5 = list[e + 5], s6 = list[e + 6], s7 = list[e + 7];
                unsigned u0 = reinterpret_cast<const unsigned*>(xb + (size_t)s0 * DIM_IN)[lane];
                unsigned u1 = reinterpret_cast<const unsigned*>(xb + (size_t)s1 * DIM_IN)[lane];
                unsigned u2 = reinterpret_cast<const unsigned*>(xb + (size_t)s2 * DIM_IN)[lane];
                unsigned u3 = reinterpret_cast<const unsigned*>(xb + (size_t)s3 * DIM_IN)[lane];
                unsigned u4 = reinterpret_cast<const unsigned*>(xb + (size_t)s4 * DIM_IN)[lane];
                unsigned u5 = reinterpret_cast<const unsigned*>(xb + (size_t)s5 * DIM_IN)[lane];
                unsigned u6 = reinterpret_cast<const unsigned*>(xb + (size_t)s6 * DIM_IN)[lane];
                unsigned u7 = reinterpret_cast<const unsigned*>(xb + (size_t)s7 * DIM_IN)[lane];
                a0 += bflo(u0) + bflo(u1);  a1 += bfhi(u0) + bfhi(u1);
                b0 += bflo(u2) + bflo(u3);  b1 += bfhi(u2) + bfhi(u3);
                c0 += bflo(u4) + bflo(u5);  c1 += bfhi(u4) + bfhi(u5);
                d0 += bflo(u6) + bflo(u7);  d1 += bfhi(u6) + bfhi(u7);
            }
            for (; e + 3 < end; e += 4) {
                int s0 = list[e], s1 = list[e + 1], s2 = list[e + 2], s3 = list[e + 3];
                unsigned u0 = reinterpret_cast<const unsigned*>(xb + (size_t)s0 * DIM_IN)[lane];
                unsigned u1 = reinterpret_cast<const unsigned*>(xb + (size_t)s1 * DIM_IN)[lane];
                unsigned u2 = reinterpret_cast<const unsigned*>(xb + (size_t)s2 * DIM_IN)[lane];
                unsigned u3 = reinterpret_cast<const unsigned*>(xb + (size_t)s3 * DIM_IN)[lane];
                a0 += bflo(u0) + bflo(u1);  a1 += bfhi(u0) + bfhi(u1);
                b0 += bflo(u2) + bflo(u3);  b1 += bfhi(u2) + bfhi(u3);
            }
            for (; e < end; ++e) {
                int s0 = list[e];
                unsigned u0 = reinterpret_cast<const unsigned*>(xb + (size_t)s0 * DIM_IN)[lane];
                a0 += bflo(u0);
                a1 += bfhi(u0);
            }
            float d = deg_inv[node];
            r0 = ((a0 + b0) + (c0 + d0)) * d;
            r1 = ((a1 + b1) + (c1 + d1)) * d;
        }
        unsigned short q0 = __builtin_bit_cast(unsigned short, (__bf16)r0);
        unsigned short q1 = __builtin_bit_cast(unsigned short, (__bf16)r1);
        unsigned packed = (unsigned)q0 | ((unsigned)q1 << 16);
        *reinterpret_cast<unsigned*>(
            &mtile[row * 256 + ((gw ^ (row & 7)) * 16) + bofs]) = packed;
    }
    __syncthreads();

    // ===== Phase 2: MFMA GEMM from LDS (exact R18 code) ====================
    bf16x8 wfr[2][4];
#pragma unroll
    for (int mt = 0; mt < 2; ++mt)
#pragma unroll
        for (int ks = 0; ks < 4; ++ks)
            wfr[mt][ks] = *reinterpret_cast<const bf16x8*>(
                Wb + (size_t)(o0 + mt * 16 + lr) * DIM_IN + ks * 32 + kg * 8);

    f32x4 bias4[2];
#pragma unroll
    for (int mt = 0; mt < 2; ++mt)
        bias4[mt] = *reinterpret_cast<const f32x4*>(bias + o0 + mt * 16 + kg * 4);

#pragma unroll
    for (int st = 0; st < NPB / 32; ++st) {
        const int nb = nb0 + st * 32;
        if (nb >= N_NODES) break;

        f32x4 acc[2][2] = {};
#pragma unroll
        for (int ks = 0; ks < 4; ++ks) {
            bf16x8 mfr[2];
#pragma unroll
            for (int nt = 0; nt < 2; ++nt) {
                const int row = st * 32 + nt * 16 + lr;
                const int g = (ks * 4 + kg) ^ (row & 7);
                mfr[nt] = *reinterpret_cast<const bf16x8*>(&mtile[row * 256 + g * 16]);
            }
#pragma unroll
            for (int mt = 0; mt < 2; ++mt)
#pragma unroll
                for (int nt = 0; nt < 2; ++nt)
                    acc[mt][nt] = __builtin_amdgcn_mfma_f32_16x16x32_bf16(
                        wfr[mt][ks], mfr[nt], acc[mt][nt], 0, 0, 0);
        }

#pragma unroll
        for (int nt = 0; nt < 2; ++nt) {
            const int node = nb + nt * 16 + lr;
            if (node < N_NODES) {
                float* orow = out + (size_t)node * DIM_OUT + o0 + kg * 4;
#pragma unroll
                for (int mt = 0; mt < 2; ++mt) {
                    f32x4 h = acc[mt][nt] + bias4[mt];
                    f32x4 g;
                    g[0] = gelu_f(h[0]);
                    g[1] = gelu_f(h[1]);
                    g[2] = gelu_f(h[2]);
                    g[3] = gelu_f(h[3]);
                    *reinterpret_cast<f32x4*>(orow + mt * 16) = g;
                }
            }
        }
    }
}

extern "C" void kernel_launch(void* const* d_in, const int* in_sizes, int n_in,
                              void* d_out, int out_size, void* d_ws, size_t ws_size,
                              hipStream_t stream) {
    const float* x       = (const float*)d_in[0];
    const int*   ei      = (const int*)d_in[1];
    const float* deg_inv = (const float*)d_in[2];
    const float* W       = (const float*)d_in[3];
    const float* bias    = (const float*)d_in[4];
    float*       out     = (float*)d_out;

    const int* src = ei;
    const int* dst = ei + N_EDGES;

    // ws layout: cnt | list | Wb | xb  (no mb buffer needed)
    int* cnt  = (int*)d_ws;
    int* list = cnt + N_NODES;
    unsigned short* Wb = (unsigned short*)(list + (size_t)N_NODES * CAP);
    unsigned short* xb = Wb + DIM_IN * DIM_OUT;

    k_prep   <<<(N_NODES * DIM_IN / 4) / 256, 256, 0, stream>>>(x, W, xb, Wb, cnt);
    k_fillpad<<<N_EDGES / 256, 256, 0, stream>>>(src, dst, cnt, list);
    k_aggemm <<<(N_NODES + NPB - 1) / NPB, 512, 0, stream>>>(xb, list, cnt, deg_inv,
                                                             Wb, bias, out);
}

// Round 22
// 138.989 us; speedup vs baseline: 1.2239x; 1.2239x over previous
//
#include <hip/hip_runtime.h>
#include <math.h>

#define N_NODES 100000
#define N_EDGES 800000
#define DIM_IN 128
#define DIM_OUT 256
#define NPB 64    // nodes per GEMM tile: 2 MFMA sub-tiles of 32
#define CAP 64    // padded CSR capacity; deg ~ Poisson(8), P(>=64) ~ 1e-36

typedef __bf16 bf16x8 __attribute__((ext_vector_type(8)));
typedef float  f32x4  __attribute__((ext_vector_type(4)));

// ---------------- prep: cvtX + cvtW + zero cnt (no atomics) ----------------
__global__ __launch_bounds__(256) void k_prep(const float* __restrict__ x,
                                              const float* __restrict__ W,
                                              unsigned short* __restrict__ xb,
                                              unsigned short* __restrict__ Wb,
                                              int* __restrict__ cnt) {
    int i = blockIdx.x * 256 + threadIdx.x;
    const float4 v = reinterpret_cast<const float4*>(x)[i];
    unsigned short s0 = __builtin_bit_cast(unsigned short, (__bf16)v.x);
    unsigned short s1 = __builtin_bit_cast(unsigned short, (__bf16)v.y);
    unsigned short s2 = __builtin_bit_cast(unsigned short, (__bf16)v.z);
    unsigned short s3 = __builtin_bit_cast(unsigned short, (__bf16)v.w);
    uint2 o;
    o.x = (unsigned)s0 | ((unsigned)s1 << 16);
    o.y = (unsigned)s2 | ((unsigned)s3 << 16);
    reinterpret_cast<uint2*>(xb)[i] = o;
    if (i < DIM_IN * DIM_OUT) Wb[i] = __builtin_bit_cast(unsigned short, (__bf16)W[i]);
    if (i < N_NODES) cnt[i] = 0;
}

// ---------------- padded-bucket CSR fill -----------------------------------
__global__ __launch_bounds__(256) void k_fillpad(const int* __restrict__ src,
                                                 const int* __restrict__ dst,
                                                 int* __restrict__ cnt,
                                                 int* __restrict__ list) {
    int e = blockIdx.x * 256 + threadIdx.x;   // grid exact: 800000/256
    int d = dst[e];
    int pos = atomicAdd(&cnt[d], 1);
    if (pos < CAP) list[(size_t)d * CAP + pos] = src[e];
}

// ---------------- Aggregate (R17/R18 proven) -------------------------------
__device__ __forceinline__ float bflo(unsigned u) {
    return __builtin_bit_cast(float, u << 16);
}
__device__ __forceinline__ float bfhi(unsigned u) {
    return __builtin_bit_cast(float, u & 0xffff0000u);
}

__global__ __launch_bounds__(256) void k_agg(const unsigned short* __restrict__ xb,
                                             const int* __restrict__ list,
                                             const int* __restrict__ cnt,
                                             const float* __restrict__ deg_inv,
                                             unsigned short* __restrict__ mb) {
    int wave = threadIdx.x >> 6;
    int lane = threadIdx.x & 63;
    int node = blockIdx.x * 4 + wave;        // grid exact: 25000*4
    int c = __builtin_amdgcn_readfirstlane(cnt[node]);
    c = c < CAP ? c : CAP;
    const int beg = node * CAP;
    const int end = beg + c;
    float a0 = 0.f, a1 = 0.f, b0 = 0.f, b1 = 0.f;
    float c0 = 0.f, c1 = 0.f, d0 = 0.f, d1 = 0.f;
    int e = beg;
    for (; e + 7 < end; e += 8) {
        int s0 = list[e],     s1 = list[e + 1], s2 = list[e + 2], s3 = list[e + 3];
        int s4 = list[e + 4], s5 = list[e + 5], s6 = list[e + 6], s7 = list[e + 7];
        unsigned u0 = reinterpret_cast<const unsigned*>(xb + (size_t)s0 * DIM_IN)[lane];
        unsigned u1 = reinterpret_cast<const unsigned*>(xb + (size_t)s1 * DIM_IN)[lane];
        unsigned u2 = reinterpret_cast<const unsigned*>(xb + (size_t)s2 * DIM_IN)[lane];
        unsigned u3 = reinterpret_cast<const unsigned*>(xb + (size_t)s3 * DIM_IN)[lane];
        unsigned u4 = reinterpret_cast<const unsigned*>(xb + (size_t)s4 * DIM_IN)[lane];
        unsigned u5 = reinterpret_cast<const unsigned*>(xb + (size_t)s5 * DIM_IN)[lane];
        unsigned u6 = reinterpret_cast<const unsigned*>(xb + (size_t)s6 * DIM_IN)[lane];
        unsigned u7 = reinterpret_cast<const unsigned*>(xb + (size_t)s7 * DIM_IN)[lane];
        a0 += bflo(u0) + bflo(u1);  a1 += bfhi(u0) + bfhi(u1);
        b0 += bflo(u2) + bflo(u3);  b1 += bfhi(u2) + bfhi(u3);
        c0 += bflo(u4) + bflo(u5);  c1 += bfhi(u4) + bfhi(u5);
        d0 += bflo(u6) + bflo(u7);  d1 += bfhi(u6) + bfhi(u7);
    }
    for (; e + 3 < end; e += 4) {
        int s0 = list[e], s1 = list[e + 1], s2 = list[e + 2], s3 = list[e + 3];
        unsigned u0 = reinterpret_cast<const unsigned*>(xb + (size_t)s0 * DIM_IN)[lane];
        unsigned u1 = reinterpret_cast<const unsigned*>(xb + (size_t)s1 * DIM_IN)[lane];
        unsigned u2 = reinterpret_cast<const unsigned*>(xb + (size_t)s2 * DIM_IN)[lane];
        unsigned u3 = reinterpret_cast<const unsigned*>(xb + (size_t)s3 * DIM_IN)[lane];
        a0 += bflo(u0) + bflo(u1);  a1 += bfhi(u0) + bfhi(u1);
        b0 += bflo(u2) + bflo(u3);  b1 += bfhi(u2) + bfhi(u3);
    }
    for (; e < end; ++e) {
        int s0 = list[e];
        unsigned u0 = reinterpret_cast<const unsigned*>(xb + (size_t)s0 * DIM_IN)[lane];
        a0 += bflo(u0);
        a1 += bfhi(u0);
    }
    float d = deg_inv[node];
    float r0 = ((a0 + b0) + (c0 + d0)) * d;
    float r1 = ((a1 + b1) + (c1 + d1)) * d;
    unsigned short q0 = __builtin_bit_cast(unsigned short, (__bf16)r0);
    unsigned short q1 = __builtin_bit_cast(unsigned short, (__bf16)r1);
    reinterpret_cast<unsigned*>(mb + (size_t)node * DIM_IN)[lane] =
        (unsigned)q0 | ((unsigned)q1 << 16);
}

// ---------------- GELU (tanh form, branch-free) ----------------------------
__device__ __forceinline__ float gelu_f(float h) {
    float u = h * h;
    float inner = h * (0.7978845608f + 0.0356774081f * u);
    float a = __builtin_amdgcn_exp2f(-2.8853900818f * __builtin_fabsf(inner));
    float t = (1.f - a) * __builtin_amdgcn_rcpf(1.f + a);
    t = __builtin_copysignf(t, inner);
    return 0.5f * h * (1.f + t);
}

// ---------------- MFMA GEMM: LDS A-panel, column-split for occupancy -------
// R18's gemm (512 thr, ~2 blocks/CU) was latency-bound: few independent
// stage->sync->compute->store chains per CU. Split the output dim: block =
// 256 thr (4 waves) owns 64 nodes x 128 out-cols (h = bid&1 selects half).
// Same per-wave code; mtile staged per block (2x total staging, L3-cheap);
// ~5 blocks/CU resident -> 2.5x more overlapping chains.
__global__ __launch_bounds__(256, 4) void k_gemm(
    const unsigned short* __restrict__ mb,
    const unsigned short* __restrict__ Wb,
    const float* __restrict__ bias,
    float* __restrict__ out)
{
    __shared__ unsigned char mtile[NPB * 256];   // 16 KB swizzled bf16 A-panel

    const int tid  = threadIdx.x;
    const int wave = tid >> 6;
    const int lane = tid & 63;
    const int lr = lane & 15;
    const int kg = lane >> 4;
    const int h  = blockIdx.x & 1;               // column half
    const int t  = blockIdx.x >> 1;              // node tile
    const int o0 = h * 128 + wave * 32;
    const int nb0 = t * NPB;

    // --- stage mb tile: 1024 16B-granules, 4 per thread, coalesced ---------
    // (last tile reads ~8KB past node 99999 -> still inside ws (cnt/list);
    //  garbage rows are never stored: epilogue guards node < N_NODES.)
#pragma unroll
    for (int p = 0; p < 4; ++p) {
        const int idx = p * 256 + tid;
        const int row = idx >> 4;        // 0..63
        const int g   = idx & 15;        // 16B granule within row
        const uint4 v = *reinterpret_cast<const uint4*>(
            mb + (size_t)(nb0 + row) * DIM_IN + g * 8);
        const int swg = g ^ (row & 7);   // bijective per row
        *reinterpret_cast<uint4*>(&mtile[row * 256 + swg * 16]) = v;
    }

    bf16x8 wfr[2][4];
#pragma unroll
    for (int mt = 0; mt < 2; ++mt)
#pragma unroll
        for (int ks = 0; ks < 4; ++ks)
            wfr[mt][ks] = *reinterpret_cast<const bf16x8*>(
                Wb + (size_t)(o0 + mt * 16 + lr) * DIM_IN + ks * 32 + kg * 8);

    f32x4 bias4[2];
#pragma unroll
    for (int mt = 0; mt < 2; ++mt)
        bias4[mt] = *reinterpret_cast<const f32x4*>(bias + o0 + mt * 16 + kg * 4);

    __syncthreads();

#pragma unroll
    for (int st = 0; st < NPB / 32; ++st) {
        const int nb = nb0 + st * 32;
        if (nb >= N_NODES) break;

        f32x4 acc[2][2] = {};
#pragma unroll
        for (int ks = 0; ks < 4; ++ks) {
            bf16x8 mfr[2];
#pragma unroll
            for (int nt = 0; nt < 2; ++nt) {
                const int row = st * 32 + nt * 16 + lr;
                const int g = (ks * 4 + kg) ^ (row & 7);
                mfr[nt] = *reinterpret_cast<const bf16x8*>(&mtile[row * 256 + g * 16]);
            }
#pragma unroll
            for (int mt = 0; mt < 2; ++mt)
#pragma unroll
                for (int nt = 0; nt < 2; ++nt)
                    acc[mt][nt] = __builtin_amdgcn_mfma_f32_16x16x32_bf16(
                        wfr[mt][ks], mfr[nt], acc[mt][nt], 0, 0, 0);
        }

#pragma unroll
        for (int nt = 0; nt < 2; ++nt) {
            const int node = nb + nt * 16 + lr;
            if (node < N_NODES) {
                float* orow = out + (size_t)node * DIM_OUT + o0 + kg * 4;
#pragma unroll
                for (int mt = 0; mt < 2; ++mt) {
                    f32x4 hh = acc[mt][nt] + bias4[mt];
                    f32x4 g;
                    g[0] = gelu_f(hh[0]);
                    g[1] = gelu_f(hh[1]);
                    g[2] = gelu_f(hh[2]);
                    g[3] = gelu_f(hh[3]);
                    *reinterpret_cast<f32x4*>(orow + mt * 16) = g;
                }
            }
        }
    }
}

extern "C" void kernel_launch(void* const* d_in, const int* in_sizes, int n_in,
                              void* d_out, int out_size, void* d_ws, size_t ws_size,
                              hipStream_t stream) {
    const float* x       = (const float*)d_in[0];
    const int*   ei      = (const int*)d_in[1];
    const float* deg_inv = (const float*)d_in[2];
    const float* W       = (const float*)d_in[3];
    const float* bias    = (const float*)d_in[4];
    float*       out     = (float*)d_out;

    const int* src = ei;
    const int* dst = ei + N_EDGES;

    // ws layout: mb | cnt | list | Wb | xb
    unsigned short* mb = (unsigned short*)d_ws;
    int* cnt  = (int*)(mb + (size_t)N_NODES * DIM_IN);
    int* list = cnt + N_NODES;
    unsigned short* Wb = (unsigned short*)(list + (size_t)N_NODES * CAP);
    unsigned short* xb = Wb + DIM_IN * DIM_OUT;

    k_prep   <<<(N_NODES * DIM_IN / 4) / 256, 256, 0, stream>>>(x, W, xb, Wb, cnt);
    k_fillpad<<<N_EDGES / 256, 256, 0, stream>>>(src, dst, cnt, list);
    k_agg    <<<N_NODES / 4, 256, 0, stream>>>(xb, list, cnt, deg_inv, mb);
    k_gemm   <<<2 * ((N_NODES + NPB - 1) / NPB), 256, 0, stream>>>(mb, Wb, bias, out);
}